// Round 5
// baseline (318.631 us; speedup 1.0000x reference)
//
#include <hip/hip_runtime.h>
#include <hip/hip_bf16.h>
#include <math.h>

// ArcFace loss, MI355X. B=2048, D=512, C=32768.
// R5: GEMM moved to MX-scaled FP8 (mfma_scale 16x16x128, scale=1.0).
// R4 analysis: bf16 kernel was LDS-read(41us)+MFMA(33us) THROUGHPUT bound;
// fp8 K=128 halves both floors (20.5/14.7us) and cuts K-iters 16->4.
// Tile 128x128, 256thr/4waves, single LDS buffer (32KB -> 3 blocks/CU).
// LDS rows are 128B of fp8; 16B chunks XOR-swizzled by (row&7) -> 2-way free.

#define BN 2048
#define DK 512
#define CN 32768

typedef __attribute__((ext_vector_type(4))) float floatx4;
typedef __attribute__((ext_vector_type(8))) int int8v;

__device__ inline float dot4(floatx4 a, floatx4 b) {
  return a.x * b.x + a.y * b.y + a.z * b.z + a.w * b.w;
}

__device__ inline int pack_fp8x4(floatx4 v) {
  // 4 fp32 -> 4 OCP e4m3 bytes (v_cvt_pk_fp8_f32)
  int r = __builtin_amdgcn_cvt_pk_fp8_f32(v.x, v.y, 0, false);
  r = __builtin_amdgcn_cvt_pk_fp8_f32(v.z, v.w, r, true);
  return r;
}

__device__ inline void async_ld16(const void* g, void* l) {
  // per-lane 16B global -> LDS at (wave-uniform base + lane*16)
  __builtin_amdgcn_global_load_lds(
      (const __attribute__((address_space(1))) void*)g,
      (__attribute__((address_space(3))) void*)l, 16, 0, 0);
}

// ---- kernel 1: fused prep -> fp8 rows (512 B each).
// blocks [0, 8192): weight rows -> normalized fp8 wb8 (4 rows/block)
// blocks [8192, 8704): features -> normalized fp8 fb8 + fp32 tgt + rowsum=0
__global__ void prep_kernel(const float* __restrict__ feat,
                            const int* __restrict__ y,
                            const float* __restrict__ w,
                            int* __restrict__ fb8,     // [BN][128] dwords
                            int* __restrict__ wb8,     // [CN][128] dwords
                            float* __restrict__ tgt,
                            float* __restrict__ rowsum) {
  const int wave = threadIdx.x >> 6;
  const int l = threadIdx.x & 63;
  if (blockIdx.x < 8192) {
    const int row = blockIdx.x * 4 + wave;
    const floatx4* src = (const floatx4*)(w + (size_t)row * DK);
    floatx4 v0 = src[l];
    floatx4 v1 = src[64 + l];
    float s = dot4(v0, v0) + dot4(v1, v1);
#pragma unroll
    for (int off = 1; off < 64; off <<= 1) s += __shfl_xor(s, off, 64);
    const float scale = 1.0f / fmaxf(sqrtf(s), 1e-12f);
    v0 *= scale; v1 *= scale;
    int* db = wb8 + (size_t)row * 128;
    db[l] = pack_fp8x4(v0);
    db[64 + l] = pack_fp8x4(v1);
  } else {
    const int i = (blockIdx.x - 8192) * 4 + wave;
    const floatx4* src = (const floatx4*)(feat + (size_t)i * DK);
    floatx4 v0 = src[l];
    floatx4 v1 = src[64 + l];
    const int cls = y[i];
    const floatx4* wr = (const floatx4*)(w + (size_t)cls * DK);
    floatx4 w0 = wr[l], w1 = wr[64 + l];
    float s  = dot4(v0, v0) + dot4(v1, v1);
    float d  = dot4(v0, w0) + dot4(v1, w1);
    float wn = dot4(w0, w0) + dot4(w1, w1);
#pragma unroll
    for (int off = 1; off < 64; off <<= 1) {
      s  += __shfl_xor(s, off, 64);
      d  += __shfl_xor(d, off, 64);
      wn += __shfl_xor(wn, off, 64);
    }
    const float fscale = 1.0f / fmaxf(sqrtf(s), 1e-12f);
    v0 *= fscale; v1 *= fscale;
    int* db = fb8 + (size_t)i * 128;
    db[l] = pack_fp8x4(v0);
    db[64 + l] = pack_fp8x4(v1);
    if (l == 0) {
      tgt[i] = d * fscale / fmaxf(sqrtf(wn), 1e-12f);
      rowsum[i] = 0.0f;
    }
  }
}

// ---- kernel 2: 128x128 MX-fp8 MFMA GEMM (16x16x128, scale=1.0) + exp row-sum.
// LDS: As/Bs 128 rows x 128 B; stored 16B chunk = logical chunk ^ (row&7).
__launch_bounds__(256, 3)
__global__ void gemm_exp_kernel(const char* __restrict__ fb8,   // [BN][512] B
                                const char* __restrict__ wb8,   // [CN][512] B
                                float* __restrict__ rowsum) {
  __shared__ char As[128 * 128];   // 16 KB
  __shared__ char Bs[128 * 128];   // 16 KB
  __shared__ float lsum[128];

  const int tid  = threadIdx.x;
  const int wave = tid >> 6;
  const int lane = tid & 63;
  const int tileM = blockIdx.x * 128;
  const int tileN = blockIdx.y * 128;

  const int wm = (wave >> 1) * 64;  // wave M offset (0 or 64)
  const int wn = (wave & 1) * 64;   // wave N offset (0 or 64)

  if (tid < 128) lsum[tid] = 0.0f;  // covered by first K-loop barrier

  floatx4 acc[4][4];
#pragma unroll
  for (int mi = 0; mi < 4; ++mi)
#pragma unroll
    for (int ni = 0; ni < 4; ++ni)
      acc[mi][ni] = (floatx4){0.f, 0.f, 0.f, 0.f};

  // staging: per iter 32 KB, 8 insts/thread (4 A + 4 B).
  // inst i of wave w covers LDS rows i*32 + w*8 + (l>>3), chunk l&7.
  // row&7 == (l>>3)&7, so fetched global chunk = (l&7) ^ ((l>>3)&7).
  const int srow = (lane >> 3);                 // 0..7 row within 8-row strip
  const int sch  = (lane & 7) ^ (srow & 7);     // swizzled global 16B chunk
  const char* gA[4];
  const char* gB[4];
#pragma unroll
  for (int i = 0; i < 4; ++i) {
    const int row = i * 32 + wave * 8 + srow;
    gA[i] = fb8 + (size_t)(tileM + row) * DK + sch * 16;
    gB[i] = wb8 + (size_t)(tileN + row) * DK + sch * 16;
  }
  char* lA = &As[wave * 1024];   // wave-uniform LDS bases (+ i*4096 per inst)
  char* lB = &Bs[wave * 1024];

  const int mrow = lane & 15;        // fragment row (M or N within 16)
  const int c0   = (lane >> 4) * 2;  // first logical 16B chunk for this lane

  for (int kk = 0; kk < 4; ++kk) {
    __syncthreads();  // prior iter's LDS reads complete
#pragma unroll
    for (int i = 0; i < 4; ++i) {
      async_ld16(gA[i], lA + i * 4096);
      async_ld16(gB[i], lB + i * 4096);
      gA[i] += 128; gB[i] += 128;
    }
    __syncthreads();  // drains vmcnt(0): tiles resident

    int8v af[4], bf[4];
#pragma unroll
    for (int mi = 0; mi < 4; ++mi) {
      const int row = wm + mi * 16 + mrow;
      const char* base = &As[row * 128];
      *(int4*)&af[mi]       = *(const int4*)(base + ((c0     ^ (row & 7)) * 16));
      *((int4*)&af[mi] + 1) = *(const int4*)(base + (((c0+1) ^ (row & 7)) * 16));
    }
#pragma unroll
    for (int ni = 0; ni < 4; ++ni) {
      const int row = wn + ni * 16 + mrow;
      const char* base = &Bs[row * 128];
      *(int4*)&bf[ni]       = *(const int4*)(base + ((c0     ^ (row & 7)) * 16));
      *((int4*)&bf[ni] + 1) = *(const int4*)(base + (((c0+1) ^ (row & 7)) * 16));
    }
#pragma unroll
    for (int mi = 0; mi < 4; ++mi)
#pragma unroll
      for (int ni = 0; ni < 4; ++ni)
        acc[mi][ni] = __builtin_amdgcn_mfma_scale_f32_16x16x128_f8f6f4(
            af[mi], bf[ni], acc[mi][ni],
            0, 0,          // cbsz=fp8(e4m3), blgp=fp8(e4m3)
            0, 127,        // A scale: opsel 0, E8M0 127 = 2^0
            0, 127);       // B scale: opsel 0, E8M0 127 = 2^0
  }

  // epilogue: rowsum[m] += sum_n exp(64 * wf[m][n])
  const int rowq = (lane >> 4) * 4;  // C/D layout: row = quad*4 + reg
#pragma unroll
  for (int mi = 0; mi < 4; ++mi) {
#pragma unroll
    for (int r = 0; r < 4; ++r) {
      float v = 0.f;
#pragma unroll
      for (int ni = 0; ni < 4; ++ni)
        v += __expf(64.0f * acc[mi][ni][r]);
      v += __shfl_xor(v, 1, 64);
      v += __shfl_xor(v, 2, 64);
      v += __shfl_xor(v, 4, 64);
      v += __shfl_xor(v, 8, 64);
      if ((lane & 15) == 0)
        atomicAdd(&lsum[wm + mi * 16 + rowq + r], v);
    }
  }
  __syncthreads();
  if (tid < 128)
    atomicAdd(&rowsum[tileM + tid], lsum[tid]);
}

// ---- kernel 3: final loss
__global__ void loss_kernel(const float* __restrict__ tgt,
                            const float* __restrict__ rowsum,
                            float* __restrict__ out) {
  __shared__ float wsum[8];
  const int t = threadIdx.x;
  float sum = 0.f;
  const float cM = 0.87758256189037271f;  // cos(0.5)
  const float sM = 0.47942553860420301f;  // sin(0.5)
  for (int i = t; i < BN; i += 512) {
    const float tg_raw = tgt[i];
    const float tg = fminf(fmaxf(tg_raw, -1.f + 1e-7f), 1.f - 1e-7f);
    const float num = 64.f * (tg * cM - sqrtf(fmaxf(1.f - tg * tg, 0.f)) * sM);
    const float den = expf(num) + rowsum[i] - expf(64.f * tg_raw);
    sum += num - logf(den);
  }
#pragma unroll
  for (int off = 1; off < 64; off <<= 1) sum += __shfl_xor(sum, off, 64);
  if ((t & 63) == 0) wsum[t >> 6] = sum;
  __syncthreads();
  if (t == 0) {
    float tot = 0.f;
#pragma unroll
    for (int k = 0; k < 8; ++k) tot += wsum[k];
    out[0] = -tot * (1.0f / (float)BN);
  }
}

extern "C" void kernel_launch(void* const* d_in, const int* in_sizes, int n_in,
                              void* d_out, int out_size, void* d_ws, size_t ws_size,
                              hipStream_t stream) {
  const float* features = (const float*)d_in[0];
  const int*   y_true   = (const int*)d_in[1];
  const float* weight   = (const float*)d_in[2];
  float* out = (float*)d_out;

  char* ws = (char*)d_ws;
  char* wb8    = ws;                          // 16 MB
  char* fb8    = ws + 16777216;               //  1 MB
  float* tgt    = (float*)(ws + 17825792);    //  8 KB
  float* rowsum = (float*)(ws + 17833984);    //  8 KB

  prep_kernel<<<8192 + 512, 256, 0, stream>>>(features, y_true, weight,
                                              (int*)fb8, (int*)wb8, tgt, rowsum);
  gemm_exp_kernel<<<dim3(BN / 128, CN / 128), 256, 0, stream>>>(fb8, wb8, rowsum);
  loss_kernel<<<1, 512, 0, stream>>>(tgt, rowsum, out);
}

// Round 6
// 317.854 us; speedup vs baseline: 1.0024x; 1.0024x over previous
//
#include <hip/hip_runtime.h>
#include <hip/hip_bf16.h>
#include <math.h>

// ArcFace loss, MI355X. B=2048, D=512, C=32768.
// R6: same MX-fp8 GEMM as R5 (mfma_scale 16x16x128, scale=1.0; layout
// verified correct, absmax=0.0) but fragments are built with whole-vector
// int4v loads + __builtin_shufflevector instead of type-punned partial
// stores. R5's punned writes defeated SROA -> af/bf arrays spilled to
// scratch (428 MB WRITE_SIZE, 10x HBM traffic, 222us). K-loop fully
// unrolled so staging pointer arrays are constant-indexed (SROA-friendly).

#define BN 2048
#define DK 512
#define CN 32768

typedef __attribute__((ext_vector_type(4))) float floatx4;
typedef __attribute__((ext_vector_type(4))) int int4v;
typedef __attribute__((ext_vector_type(8))) int int8v;

__device__ inline float dot4(floatx4 a, floatx4 b) {
  return a.x * b.x + a.y * b.y + a.z * b.z + a.w * b.w;
}

__device__ inline int pack_fp8x4(floatx4 v) {
  // 4 fp32 -> 4 OCP e4m3 bytes (v_cvt_pk_fp8_f32)
  int r = __builtin_amdgcn_cvt_pk_fp8_f32(v.x, v.y, 0, false);
  r = __builtin_amdgcn_cvt_pk_fp8_f32(v.z, v.w, r, true);
  return r;
}

__device__ inline void async_ld16(const void* g, void* l) {
  // per-lane 16B global -> LDS at (wave-uniform base + lane*16)
  __builtin_amdgcn_global_load_lds(
      (const __attribute__((address_space(1))) void*)g,
      (__attribute__((address_space(3))) void*)l, 16, 0, 0);
}

// whole-vector fragment build: two 16B LDS loads -> one 8-dword fragment.
__device__ inline int8v ld_frag(const char* p0, const char* p1) {
  int4v lo = *(const int4v*)p0;
  int4v hi = *(const int4v*)p1;
  return __builtin_shufflevector(lo, hi, 0, 1, 2, 3, 4, 5, 6, 7);
}

// ---- kernel 1: fused prep -> fp8 rows (512 B each).
// blocks [0, 8192): weight rows -> normalized fp8 wb8 (4 rows/block)
// blocks [8192, 8704): features -> normalized fp8 fb8 + fp32 tgt + rowsum=0
__global__ void prep_kernel(const float* __restrict__ feat,
                            const int* __restrict__ y,
                            const float* __restrict__ w,
                            int* __restrict__ fb8,     // [BN][128] dwords
                            int* __restrict__ wb8,     // [CN][128] dwords
                            float* __restrict__ tgt,
                            float* __restrict__ rowsum) {
  const int wave = threadIdx.x >> 6;
  const int l = threadIdx.x & 63;
  if (blockIdx.x < 8192) {
    const int row = blockIdx.x * 4 + wave;
    const floatx4* src = (const floatx4*)(w + (size_t)row * DK);
    floatx4 v0 = src[l];
    floatx4 v1 = src[64 + l];
    float s = dot4(v0, v0) + dot4(v1, v1);
#pragma unroll
    for (int off = 1; off < 64; off <<= 1) s += __shfl_xor(s, off, 64);
    const float scale = 1.0f / fmaxf(sqrtf(s), 1e-12f);
    v0 *= scale; v1 *= scale;
    int* db = wb8 + (size_t)row * 128;
    db[l] = pack_fp8x4(v0);
    db[64 + l] = pack_fp8x4(v1);
  } else {
    const int i = (blockIdx.x - 8192) * 4 + wave;
    const floatx4* src = (const floatx4*)(feat + (size_t)i * DK);
    floatx4 v0 = src[l];
    floatx4 v1 = src[64 + l];
    const int cls = y[i];
    const floatx4* wr = (const floatx4*)(w + (size_t)cls * DK);
    floatx4 w0 = wr[l], w1 = wr[64 + l];
    float s  = dot4(v0, v0) + dot4(v1, v1);
    float d  = dot4(v0, w0) + dot4(v1, w1);
    float wn = dot4(w0, w0) + dot4(w1, w1);
#pragma unroll
    for (int off = 1; off < 64; off <<= 1) {
      s  += __shfl_xor(s, off, 64);
      d  += __shfl_xor(d, off, 64);
      wn += __shfl_xor(wn, off, 64);
    }
    const float fscale = 1.0f / fmaxf(sqrtf(s), 1e-12f);
    v0 *= fscale; v1 *= fscale;
    int* db = fb8 + (size_t)i * 128;
    db[l] = pack_fp8x4(v0);
    db[64 + l] = pack_fp8x4(v1);
    if (l == 0) {
      tgt[i] = d * fscale / fmaxf(sqrtf(wn), 1e-12f);
      rowsum[i] = 0.0f;
    }
  }
}

// ---- kernel 2: 128x128 MX-fp8 MFMA GEMM (16x16x128, scale=1.0) + exp row-sum.
// LDS: As/Bs 128 rows x 128 B; stored 16B chunk = logical chunk ^ (row&7).
__launch_bounds__(256, 3)
__global__ void gemm_exp_kernel(const char* __restrict__ fb8,   // [BN][512] B
                                const char* __restrict__ wb8,   // [CN][512] B
                                float* __restrict__ rowsum) {
  __shared__ char As[128 * 128];   // 16 KB
  __shared__ char Bs[128 * 128];   // 16 KB
  __shared__ float lsum[128];

  const int tid  = threadIdx.x;
  const int wave = tid >> 6;
  const int lane = tid & 63;
  const int tileM = blockIdx.x * 128;
  const int tileN = blockIdx.y * 128;

  const int wm = (wave >> 1) * 64;  // wave M offset (0 or 64)
  const int wn = (wave & 1) * 64;   // wave N offset (0 or 64)

  if (tid < 128) lsum[tid] = 0.0f;  // covered by first K-loop barrier

  floatx4 acc[4][4];
#pragma unroll
  for (int mi = 0; mi < 4; ++mi)
#pragma unroll
    for (int ni = 0; ni < 4; ++ni)
      acc[mi][ni] = (floatx4){0.f, 0.f, 0.f, 0.f};

  // staging: per iter 32 KB, 8 insts/thread (4 A + 4 B).
  // inst i of wave w covers LDS rows i*32 + w*8 + (l>>3), chunk l&7.
  // row&7 == (l>>3)&7, so fetched global chunk = (l&7) ^ ((l>>3)&7).
  const int srow = (lane >> 3);                 // 0..7 row within 8-row strip
  const int sch  = (lane & 7) ^ (srow & 7);     // swizzled global 16B chunk
  const char* gA[4];
  const char* gB[4];
#pragma unroll
  for (int i = 0; i < 4; ++i) {
    const int row = i * 32 + wave * 8 + srow;
    gA[i] = fb8 + (size_t)(tileM + row) * DK + sch * 16;
    gB[i] = wb8 + (size_t)(tileN + row) * DK + sch * 16;
  }
  char* lA = &As[wave * 1024];   // wave-uniform LDS bases (+ i*4096 per inst)
  char* lB = &Bs[wave * 1024];

  const int mrow = lane & 15;        // fragment row (M or N within 16)
  const int c0   = (lane >> 4) * 2;  // first logical 16B chunk for this lane

#pragma unroll
  for (int kk = 0; kk < 4; ++kk) {
    __syncthreads();  // prior iter's LDS reads complete
#pragma unroll
    for (int i = 0; i < 4; ++i) {
      async_ld16(gA[i], lA + i * 4096);
      async_ld16(gB[i], lB + i * 4096);
      gA[i] += 128; gB[i] += 128;
    }
    __syncthreads();  // drains vmcnt(0): tiles resident

    int8v af[4], bf[4];
#pragma unroll
    for (int mi = 0; mi < 4; ++mi) {
      const int row = wm + mi * 16 + mrow;
      const char* base = &As[row * 128];
      af[mi] = ld_frag(base + ((c0 ^ (row & 7)) * 16),
                       base + (((c0 + 1) ^ (row & 7)) * 16));
    }
#pragma unroll
    for (int ni = 0; ni < 4; ++ni) {
      const int row = wn + ni * 16 + mrow;
      const char* base = &Bs[row * 128];
      bf[ni] = ld_frag(base + ((c0 ^ (row & 7)) * 16),
                       base + (((c0 + 1) ^ (row & 7)) * 16));
    }
#pragma unroll
    for (int mi = 0; mi < 4; ++mi)
#pragma unroll
      for (int ni = 0; ni < 4; ++ni)
        acc[mi][ni] = __builtin_amdgcn_mfma_scale_f32_16x16x128_f8f6f4(
            af[mi], bf[ni], acc[mi][ni],
            0, 0,          // cbsz=fp8(e4m3), blgp=fp8(e4m3)
            0, 127,        // A scale: opsel 0, E8M0 127 = 2^0
            0, 127);       // B scale: opsel 0, E8M0 127 = 2^0
  }

  // epilogue: rowsum[m] += sum_n exp(64 * wf[m][n])
  const int rowq = (lane >> 4) * 4;  // C/D layout: row = quad*4 + reg
#pragma unroll
  for (int mi = 0; mi < 4; ++mi) {
#pragma unroll
    for (int r = 0; r < 4; ++r) {
      float v = 0.f;
#pragma unroll
      for (int ni = 0; ni < 4; ++ni)
        v += __expf(64.0f * acc[mi][ni][r]);
      v += __shfl_xor(v, 1, 64);
      v += __shfl_xor(v, 2, 64);
      v += __shfl_xor(v, 4, 64);
      v += __shfl_xor(v, 8, 64);
      if ((lane & 15) == 0)
        atomicAdd(&lsum[wm + mi * 16 + rowq + r], v);
    }
  }
  __syncthreads();
  if (tid < 128)
    atomicAdd(&rowsum[tileM + tid], lsum[tid]);
}

// ---- kernel 3: final loss
__global__ void loss_kernel(const float* __restrict__ tgt,
                            const float* __restrict__ rowsum,
                            float* __restrict__ out) {
  __shared__ float wsum[8];
  const int t = threadIdx.x;
  float sum = 0.f;
  const float cM = 0.87758256189037271f;  // cos(0.5)
  const float sM = 0.47942553860420301f;  // sin(0.5)
  for (int i = t; i < BN; i += 512) {
    const float tg_raw = tgt[i];
    const float tg = fminf(fmaxf(tg_raw, -1.f + 1e-7f), 1.f - 1e-7f);
    const float num = 64.f * (tg * cM - sqrtf(fmaxf(1.f - tg * tg, 0.f)) * sM);
    const float den = expf(num) + rowsum[i] - expf(64.f * tg_raw);
    sum += num - logf(den);
  }
#pragma unroll
  for (int off = 1; off < 64; off <<= 1) sum += __shfl_xor(sum, off, 64);
  if ((t & 63) == 0) wsum[t >> 6] = sum;
  __syncthreads();
  if (t == 0) {
    float tot = 0.f;
#pragma unroll
    for (int k = 0; k < 8; ++k) tot += wsum[k];
    out[0] = -tot * (1.0f / (float)BN);
  }
}

extern "C" void kernel_launch(void* const* d_in, const int* in_sizes, int n_in,
                              void* d_out, int out_size, void* d_ws, size_t ws_size,
                              hipStream_t stream) {
  const float* features = (const float*)d_in[0];
  const int*   y_true   = (const int*)d_in[1];
  const float* weight   = (const float*)d_in[2];
  float* out = (float*)d_out;

  char* ws = (char*)d_ws;
  char* wb8    = ws;                          // 16 MB
  char* fb8    = ws + 16777216;               //  1 MB
  float* tgt    = (float*)(ws + 17825792);    //  8 KB
  float* rowsum = (float*)(ws + 17833984);    //  8 KB

  prep_kernel<<<8192 + 512, 256, 0, stream>>>(features, y_true, weight,
                                              (int*)fb8, (int*)wb8, tgt, rowsum);
  gemm_exp_kernel<<<dim3(BN / 128, CN / 128), 256, 0, stream>>>(fb8, wb8, rowsum);
  loss_kernel<<<1, 512, 0, stream>>>(tgt, rowsum, out);
}

// Round 7
// 161.311 us; speedup vs baseline: 1.9753x; 1.9704x over previous
//
#include <hip/hip_runtime.h>
#include <hip/hip_bf16.h>
#include <math.h>

// ArcFace loss, MI355X. B=2048, D=512, C=32768.
// R7: non-scaled fp8 GEMM (mfma_f32_16x16x32_fp8_fp8, i64 operands — same
// clean codegen family as bf16; the scaled-MX intrinsic caused ~800MB of
// scratch round-trip in R5/R6). fp8 halves LDS+staging bytes vs bf16
// (LDS floor ~21us < MFMA floor ~34us -> MFMA-bound). 128x256 tile,
// 512thr/8waves, K=64/iter. LDS rows 64B, 16B-granule XOR swizzle
// (u16 ^= (row>>1)&3): b64 reads land 4 lanes/bank-pair = b64 floor.
// XCD-aware block swizzle: XCD k (= n%8 round-robin) owns N-tiles y≡k(8),
// sweeping M fast -> each B-tile fetched by exactly one XCD.

#define BN 2048
#define DK 512
#define CN 32768

typedef __attribute__((ext_vector_type(4))) float floatx4;

__device__ inline float dot4(floatx4 a, floatx4 b) {
  return a.x * b.x + a.y * b.y + a.z * b.z + a.w * b.w;
}

__device__ inline int pack_fp8x4(floatx4 v) {
  // 4 fp32 -> 4 OCP e4m3 bytes (v_cvt_pk_fp8_f32)
  int r = __builtin_amdgcn_cvt_pk_fp8_f32(v.x, v.y, 0, false);
  r = __builtin_amdgcn_cvt_pk_fp8_f32(v.z, v.w, r, true);
  return r;
}

__device__ inline void async_ld16(const void* g, void* l) {
  // per-lane 16B global -> LDS at (wave-uniform base + lane*16)
  __builtin_amdgcn_global_load_lds(
      (const __attribute__((address_space(1))) void*)g,
      (__attribute__((address_space(3))) void*)l, 16, 0, 0);
}

// ---- kernel 1: fused prep -> fp8 rows (512 B each).
// blocks [0, 8192): weight rows -> normalized fp8 wb8 (4 rows/block)
// blocks [8192, 8704): features -> normalized fp8 fb8 + fp32 tgt + rowsum=0
__global__ void prep_kernel(const float* __restrict__ feat,
                            const int* __restrict__ y,
                            const float* __restrict__ w,
                            int* __restrict__ fb8,     // [BN][128] dwords
                            int* __restrict__ wb8,     // [CN][128] dwords
                            float* __restrict__ tgt,
                            float* __restrict__ rowsum) {
  const int wave = threadIdx.x >> 6;
  const int l = threadIdx.x & 63;
  if (blockIdx.x < 8192) {
    const int row = blockIdx.x * 4 + wave;
    const floatx4* src = (const floatx4*)(w + (size_t)row * DK);
    floatx4 v0 = src[l];
    floatx4 v1 = src[64 + l];
    float s = dot4(v0, v0) + dot4(v1, v1);
#pragma unroll
    for (int off = 1; off < 64; off <<= 1) s += __shfl_xor(s, off, 64);
    const float scale = 1.0f / fmaxf(sqrtf(s), 1e-12f);
    v0 *= scale; v1 *= scale;
    int* db = wb8 + (size_t)row * 128;
    db[l] = pack_fp8x4(v0);
    db[64 + l] = pack_fp8x4(v1);
  } else {
    const int i = (blockIdx.x - 8192) * 4 + wave;
    const floatx4* src = (const floatx4*)(feat + (size_t)i * DK);
    floatx4 v0 = src[l];
    floatx4 v1 = src[64 + l];
    const int cls = y[i];
    const floatx4* wr = (const floatx4*)(w + (size_t)cls * DK);
    floatx4 w0 = wr[l], w1 = wr[64 + l];
    float s  = dot4(v0, v0) + dot4(v1, v1);
    float d  = dot4(v0, w0) + dot4(v1, w1);
    float wn = dot4(w0, w0) + dot4(w1, w1);
#pragma unroll
    for (int off = 1; off < 64; off <<= 1) {
      s  += __shfl_xor(s, off, 64);
      d  += __shfl_xor(d, off, 64);
      wn += __shfl_xor(wn, off, 64);
    }
    const float fscale = 1.0f / fmaxf(sqrtf(s), 1e-12f);
    v0 *= fscale; v1 *= fscale;
    int* db = fb8 + (size_t)i * 128;
    db[l] = pack_fp8x4(v0);
    db[64 + l] = pack_fp8x4(v1);
    if (l == 0) {
      tgt[i] = d * fscale / fmaxf(sqrtf(wn), 1e-12f);
      rowsum[i] = 0.0f;
    }
  }
}

// ---- kernel 2: 128(M)x256(N) fp8 MFMA GEMM (16x16x32) + fused exp row-sum.
// LDS: As 128x64B, Bs 256x64B (one K=64 slab); stored 16B unit = u ^ ((row>>1)&3).
__launch_bounds__(512, 4)
__global__ void gemm_exp_kernel(const char* __restrict__ fb8,   // [BN][512] B
                                const char* __restrict__ wb8,   // [CN][512] B
                                float* __restrict__ rowsum) {
  __shared__ char As[128 * 64];   //  8 KB
  __shared__ char Bs[256 * 64];   // 16 KB
  __shared__ float lsum[128];

  const int tid  = threadIdx.x;
  const int wave = tid >> 6;
  const int lane = tid & 63;

  // XCD swizzle: n -> (x: M-tile 0..15, y: N-tile 0..127); XCD(n%8) owns y%8.
  const int n = blockIdx.x;
  const int tileM = ((n >> 3) & 15) * 128;
  const int tileN = (((n >> 7) << 3) | (n & 7)) * 256;

  const int wm = (wave >> 2) * 64;  // wave M offset (0 or 64)
  const int wn = (wave & 3) * 64;   // wave N offset (0..192)

  if (tid < 128) lsum[tid] = 0.0f;  // covered by first K-loop barrier

  floatx4 acc[4][4];
#pragma unroll
  for (int mi = 0; mi < 4; ++mi)
#pragma unroll
    for (int ni = 0; ni < 4; ++ni)
      acc[mi][ni] = (floatx4){0.f, 0.f, 0.f, 0.f};

  // staging: per iter A 512 + B 1024 16B-chunks, 3 insts/thread.
  // chunk c: row c>>2, stored unit c&3; fetch global unit (c&3)^((row>>1)&3).
  const int mA = tid >> 2;                    // A row 0..127
  const int uA = (tid & 3) ^ ((mA >> 1) & 3); // global 16B unit
  const int mB0 = tid >> 2;                   // B rows 0..127 (inst 0)
  const int uB0 = (tid & 3) ^ ((mB0 >> 1) & 3);
  const int mB1 = (512 + tid) >> 2;           // B rows 128..255 (inst 1)
  const int uB1 = (tid & 3) ^ ((mB1 >> 1) & 3);
  const char* gA  = fb8 + (size_t)(tileM + mA)  * DK + uA  * 16;
  const char* gB0 = wb8 + (size_t)(tileN + mB0) * DK + uB0 * 16;
  const char* gB1 = wb8 + (size_t)(tileN + mB1) * DK + uB1 * 16;
  char* lA  = &As[wave * 1024];   // wave-uniform LDS bases
  char* lB0 = &Bs[wave * 1024];
  char* lB1 = &Bs[8192 + wave * 1024];

  const int mrow = lane & 15;   // fragment row (M or N within 16)
  const int q    = lane >> 4;   // quad: k = q*8 + j
  const int qh   = q >> 1;      // u16 contribution
  const int qb   = (q & 1) * 8; // sub-8B offset

  for (int kk = 0; kk < DK / 64; ++kk) {
    __syncthreads();  // prior iter's LDS reads complete
    async_ld16(gA,  lA);
    async_ld16(gB0, lB0);
    async_ld16(gB1, lB1);
    gA += 64; gB0 += 64; gB1 += 64;
    __syncthreads();  // drains vmcnt(0): slab resident

#pragma unroll
    for (int p = 0; p < 2; ++p) {
      long af[4], bf[4];
#pragma unroll
      for (int mi = 0; mi < 4; ++mi) {
        const int row = wm + mi * 16 + mrow;
        const int st = (2 * p + qh) ^ ((row >> 1) & 3);
        af[mi] = *(const long*)&As[row * 64 + st * 16 + qb];
      }
#pragma unroll
      for (int ni = 0; ni < 4; ++ni) {
        const int row = wn + ni * 16 + mrow;
        const int st = (2 * p + qh) ^ ((row >> 1) & 3);
        bf[ni] = *(const long*)&Bs[row * 64 + st * 16 + qb];
      }
#pragma unroll
      for (int mi = 0; mi < 4; ++mi)
#pragma unroll
        for (int ni = 0; ni < 4; ++ni)
          acc[mi][ni] = __builtin_amdgcn_mfma_f32_16x16x32_fp8_fp8(
              af[mi], bf[ni], acc[mi][ni], 0, 0, 0);
    }
  }

  // epilogue: rowsum[m] += sum_n exp(64 * wf[m][n])
  const int rowq = (lane >> 4) * 4;  // C/D layout: row = quad*4 + reg
#pragma unroll
  for (int mi = 0; mi < 4; ++mi) {
#pragma unroll
    for (int r = 0; r < 4; ++r) {
      float v = 0.f;
#pragma unroll
      for (int ni = 0; ni < 4; ++ni)
        v += __expf(64.0f * acc[mi][ni][r]);
      v += __shfl_xor(v, 1, 64);
      v += __shfl_xor(v, 2, 64);
      v += __shfl_xor(v, 4, 64);
      v += __shfl_xor(v, 8, 64);
      if ((lane & 15) == 0)
        atomicAdd(&lsum[wm + mi * 16 + rowq + r], v);
    }
  }
  __syncthreads();
  if (tid < 128)
    atomicAdd(&rowsum[tileM + tid], lsum[tid]);
}

// ---- kernel 3: final loss
__global__ void loss_kernel(const float* __restrict__ tgt,
                            const float* __restrict__ rowsum,
                            float* __restrict__ out) {
  __shared__ float wsum[8];
  const int t = threadIdx.x;
  float sum = 0.f;
  const float cM = 0.87758256189037271f;  // cos(0.5)
  const float sM = 0.47942553860420301f;  // sin(0.5)
  for (int i = t; i < BN; i += 512) {
    const float tg_raw = tgt[i];
    const float tg = fminf(fmaxf(tg_raw, -1.f + 1e-7f), 1.f - 1e-7f);
    const float num = 64.f * (tg * cM - sqrtf(fmaxf(1.f - tg * tg, 0.f)) * sM);
    const float den = expf(num) + rowsum[i] - expf(64.f * tg_raw);
    sum += num - logf(den);
  }
#pragma unroll
  for (int off = 1; off < 64; off <<= 1) sum += __shfl_xor(sum, off, 64);
  if ((t & 63) == 0) wsum[t >> 6] = sum;
  __syncthreads();
  if (t == 0) {
    float tot = 0.f;
#pragma unroll
    for (int k = 0; k < 8; ++k) tot += wsum[k];
    out[0] = -tot * (1.0f / (float)BN);
  }
}

extern "C" void kernel_launch(void* const* d_in, const int* in_sizes, int n_in,
                              void* d_out, int out_size, void* d_ws, size_t ws_size,
                              hipStream_t stream) {
  const float* features = (const float*)d_in[0];
  const int*   y_true   = (const int*)d_in[1];
  const float* weight   = (const float*)d_in[2];
  float* out = (float*)d_out;

  char* ws = (char*)d_ws;
  char* wb8    = ws;                          // 16 MB
  char* fb8    = ws + 16777216;               //  1 MB
  float* tgt    = (float*)(ws + 17825792);    //  8 KB
  float* rowsum = (float*)(ws + 17833984);    //  8 KB

  prep_kernel<<<8192 + 512, 256, 0, stream>>>(features, y_true, weight,
                                              (int*)fb8, (int*)wb8, tgt, rowsum);
  gemm_exp_kernel<<<2048, 512, 0, stream>>>(fb8, wb8, rowsum);
  loss_kernel<<<1, 512, 0, stream>>>(tgt, rowsum, out);
}

// Round 8
// 158.634 us; speedup vs baseline: 2.0086x; 1.0169x over previous
//
#include <hip/hip_runtime.h>
#include <hip/hip_bf16.h>
#include <math.h>

// ArcFace loss, MI355X. B=2048, D=512, C=32768.
// R8: fp8 GEMM (mfma_f32_16x16x32_fp8_fp8) with MFMA-READY global layout:
// prep permutes each 64B k-slab so 16B unit u = k[8u..8u+8) ++ k[8u+32..+8)
// (lane-quad q's p=0 and p=1 fragments contiguous). Fragment reads become
// one ds_read_b128 per operand per K-64 slab in the R2-verified pattern
// (64B rows, unit ^= (row>>1)&3) = 0 bank conflicts, vs R7's ds_read_b64
// 4-way structural conflicts (+4 cyc/read, ~14us). LDS floor 20.5us < MFMA
// floor 33us -> MFMA-bound. XCD swizzle kept (R7: FETCH 135->12 MB).

#define BN 2048
#define DK 512
#define CN 32768

typedef __attribute__((ext_vector_type(4))) float floatx4;
typedef __attribute__((ext_vector_type(2))) long longx2;

__device__ inline float dot4(floatx4 a, floatx4 b) {
  return a.x * b.x + a.y * b.y + a.z * b.z + a.w * b.w;
}

__device__ inline int pack_fp8x4(floatx4 v) {
  // 4 fp32 -> 4 OCP e4m3 bytes (v_cvt_pk_fp8_f32)
  int r = __builtin_amdgcn_cvt_pk_fp8_f32(v.x, v.y, 0, false);
  r = __builtin_amdgcn_cvt_pk_fp8_f32(v.z, v.w, r, true);
  return r;
}

// dword j (0..15) of a 64B slab -> MFMA-ready position:
// q=(j>>1)&3 (8B piece), p=j>>3 (k-step), dest = q*4 + p*2 + (j&1)
__device__ inline int permute16(int j) {
  return ((j >> 1) & 3) * 4 + (j >> 3) * 2 + (j & 1);
}

__device__ inline void async_ld16(const void* g, void* l) {
  // per-lane 16B global -> LDS at (wave-uniform base + lane*16)
  __builtin_amdgcn_global_load_lds(
      (const __attribute__((address_space(1))) void*)g,
      (__attribute__((address_space(3))) void*)l, 16, 0, 0);
}

// ---- kernel 1: fused prep -> fp8 rows (512 B each), MFMA-ready byte order.
// blocks [0, 8192): weight rows -> normalized fp8 wb8 (4 rows/block)
// blocks [8192, 8704): features -> normalized fp8 fb8 + fp32 tgt + rowsum=0
__global__ void prep_kernel(const float* __restrict__ feat,
                            const int* __restrict__ y,
                            const float* __restrict__ w,
                            int* __restrict__ fb8,     // [BN][128] dwords
                            int* __restrict__ wb8,     // [CN][128] dwords
                            float* __restrict__ tgt,
                            float* __restrict__ rowsum) {
  const int wave = threadIdx.x >> 6;
  const int l = threadIdx.x & 63;
  // lane l covers source dwords l (k=4l) and 64+l; permuted destinations:
  const int d0 = ((l >> 4) * 16)     + permute16(l & 15);
  const int d1 = ((4 + (l >> 4)) * 16) + permute16(l & 15);
  if (blockIdx.x < 8192) {
    const int row = blockIdx.x * 4 + wave;
    const floatx4* src = (const floatx4*)(w + (size_t)row * DK);
    floatx4 v0 = src[l];
    floatx4 v1 = src[64 + l];
    float s = dot4(v0, v0) + dot4(v1, v1);
#pragma unroll
    for (int off = 1; off < 64; off <<= 1) s += __shfl_xor(s, off, 64);
    const float scale = 1.0f / fmaxf(sqrtf(s), 1e-12f);
    v0 *= scale; v1 *= scale;
    int* db = wb8 + (size_t)row * 128;
    db[d0] = pack_fp8x4(v0);
    db[d1] = pack_fp8x4(v1);
  } else {
    const int i = (blockIdx.x - 8192) * 4 + wave;
    const floatx4* src = (const floatx4*)(feat + (size_t)i * DK);
    floatx4 v0 = src[l];
    floatx4 v1 = src[64 + l];
    const int cls = y[i];
    const floatx4* wr = (const floatx4*)(w + (size_t)cls * DK);
    floatx4 w0 = wr[l], w1 = wr[64 + l];
    float s  = dot4(v0, v0) + dot4(v1, v1);
    float d  = dot4(v0, w0) + dot4(v1, w1);
    float wn = dot4(w0, w0) + dot4(w1, w1);
#pragma unroll
    for (int off = 1; off < 64; off <<= 1) {
      s  += __shfl_xor(s, off, 64);
      d  += __shfl_xor(d, off, 64);
      wn += __shfl_xor(wn, off, 64);
    }
    const float fscale = 1.0f / fmaxf(sqrtf(s), 1e-12f);
    v0 *= fscale; v1 *= fscale;
    int* db = fb8 + (size_t)i * 128;
    db[d0] = pack_fp8x4(v0);
    db[d1] = pack_fp8x4(v1);
    if (l == 0) {
      tgt[i] = d * fscale / fmaxf(sqrtf(wn), 1e-12f);
      rowsum[i] = 0.0f;
    }
  }
}

// ---- kernel 2: 128(M)x256(N) fp8 MFMA GEMM (16x16x32) + fused exp row-sum.
// LDS: As 128x64B, Bs 256x64B (one K=64 slab); stored 16B unit = u ^ ((row>>1)&3).
__launch_bounds__(512, 4)
__global__ void gemm_exp_kernel(const char* __restrict__ fb8,   // [BN][512] B
                                const char* __restrict__ wb8,   // [CN][512] B
                                float* __restrict__ rowsum) {
  __shared__ char As[128 * 64];   //  8 KB
  __shared__ char Bs[256 * 64];   // 16 KB
  __shared__ float lsum[128];

  const int tid  = threadIdx.x;
  const int wave = tid >> 6;
  const int lane = tid & 63;

  // XCD swizzle: n -> (x: M-tile 0..15, y: N-tile 0..127); XCD(n%8) owns y%8.
  const int n = blockIdx.x;
  const int tileM = ((n >> 3) & 15) * 128;
  const int tileN = (((n >> 7) << 3) | (n & 7)) * 256;

  const int wm = (wave >> 2) * 64;  // wave M offset (0 or 64)
  const int wn = (wave & 3) * 64;   // wave N offset (0..192)

  if (tid < 128) lsum[tid] = 0.0f;  // covered by first K-loop barrier

  floatx4 acc[4][4];
#pragma unroll
  for (int mi = 0; mi < 4; ++mi)
#pragma unroll
    for (int ni = 0; ni < 4; ++ni)
      acc[mi][ni] = (floatx4){0.f, 0.f, 0.f, 0.f};

  // staging: per iter A 512 + B 1024 16B-units, 3 insts/thread.
  // unit c: row c>>2, stored pos c&3; fetch global unit (c&3)^((row>>1)&3).
  const int mA = tid >> 2;                    // A row 0..127
  const int uA = (tid & 3) ^ ((mA >> 1) & 3); // global 16B unit
  const int mB0 = tid >> 2;                   // B rows 0..127 (inst 0)
  const int uB0 = (tid & 3) ^ ((mB0 >> 1) & 3);
  const int mB1 = (512 + tid) >> 2;           // B rows 128..255 (inst 1)
  const int uB1 = (tid & 3) ^ ((mB1 >> 1) & 3);
  const char* gA  = fb8 + (size_t)(tileM + mA)  * DK + uA  * 16;
  const char* gB0 = wb8 + (size_t)(tileN + mB0) * DK + uB0 * 16;
  const char* gB1 = wb8 + (size_t)(tileN + mB1) * DK + uB1 * 16;
  char* lA  = &As[wave * 1024];   // wave-uniform LDS bases
  char* lB0 = &Bs[wave * 1024];
  char* lB1 = &Bs[8192 + wave * 1024];

  const int mrow = lane & 15;   // fragment row (M or N within 16)
  const int q    = lane >> 4;   // quad -> logical 16B unit (p0|p1 pieces)

  for (int kk = 0; kk < DK / 64; ++kk) {
    __syncthreads();  // prior iter's LDS reads complete
    async_ld16(gA,  lA);
    async_ld16(gB0, lB0);
    async_ld16(gB1, lB1);
    gA += 64; gB0 += 64; gB1 += 64;
    __syncthreads();  // drains vmcnt(0): slab resident

    // one b128 per operand: .x = p=0 fragment (k 32*0+8q..), .y = p=1
    long af0[4], af1[4], bf0[4], bf1[4];
#pragma unroll
    for (int mi = 0; mi < 4; ++mi) {
      const int row = wm + mi * 16 + mrow;
      const int st = q ^ ((row >> 1) & 3);
      longx2 t = *(const longx2*)&As[row * 64 + st * 16];
      af0[mi] = t.x; af1[mi] = t.y;
    }
#pragma unroll
    for (int ni = 0; ni < 4; ++ni) {
      const int row = wn + ni * 16 + mrow;
      const int st = q ^ ((row >> 1) & 3);
      longx2 t = *(const longx2*)&Bs[row * 64 + st * 16];
      bf0[ni] = t.x; bf1[ni] = t.y;
    }
#pragma unroll
    for (int mi = 0; mi < 4; ++mi)
#pragma unroll
      for (int ni = 0; ni < 4; ++ni)
        acc[mi][ni] = __builtin_amdgcn_mfma_f32_16x16x32_fp8_fp8(
            af0[mi], bf0[ni], acc[mi][ni], 0, 0, 0);
#pragma unroll
    for (int mi = 0; mi < 4; ++mi)
#pragma unroll
      for (int ni = 0; ni < 4; ++ni)
        acc[mi][ni] = __builtin_amdgcn_mfma_f32_16x16x32_fp8_fp8(
            af1[mi], bf1[ni], acc[mi][ni], 0, 0, 0);
  }

  // epilogue: rowsum[m] += sum_n exp(64 * wf[m][n])
  const int rowq = (lane >> 4) * 4;  // C/D layout: row = quad*4 + reg
#pragma unroll
  for (int mi = 0; mi < 4; ++mi) {
#pragma unroll
    for (int r = 0; r < 4; ++r) {
      float v = 0.f;
#pragma unroll
      for (int ni = 0; ni < 4; ++ni)
        v += __expf(64.0f * acc[mi][ni][r]);
      v += __shfl_xor(v, 1, 64);
      v += __shfl_xor(v, 2, 64);
      v += __shfl_xor(v, 4, 64);
      v += __shfl_xor(v, 8, 64);
      if ((lane & 15) == 0)
        atomicAdd(&lsum[wm + mi * 16 + rowq + r], v);
    }
  }
  __syncthreads();
  if (tid < 128)
    atomicAdd(&rowsum[tileM + tid], lsum[tid]);
}

// ---- kernel 3: final loss
__global__ void loss_kernel(const float* __restrict__ tgt,
                            const float* __restrict__ rowsum,
                            float* __restrict__ out) {
  __shared__ float wsum[8];
  const int t = threadIdx.x;
  float sum = 0.f;
  const float cM = 0.87758256189037271f;  // cos(0.5)
  const float sM = 0.47942553860420301f;  // sin(0.5)
  for (int i = t; i < BN; i += 512) {
    const float tg_raw = tgt[i];
    const float tg = fminf(fmaxf(tg_raw, -1.f + 1e-7f), 1.f - 1e-7f);
    const float num = 64.f * (tg * cM - sqrtf(fmaxf(1.f - tg * tg, 0.f)) * sM);
    const float den = expf(num) + rowsum[i] - expf(64.f * tg_raw);
    sum += num - logf(den);
  }
#pragma unroll
  for (int off = 1; off < 64; off <<= 1) sum += __shfl_xor(sum, off, 64);
  if ((t & 63) == 0) wsum[t >> 6] = sum;
  __syncthreads();
  if (t == 0) {
    float tot = 0.f;
#pragma unroll
    for (int k = 0; k < 8; ++k) tot += wsum[k];
    out[0] = -tot * (1.0f / (float)BN);
  }
}

extern "C" void kernel_launch(void* const* d_in, const int* in_sizes, int n_in,
                              void* d_out, int out_size, void* d_ws, size_t ws_size,
                              hipStream_t stream) {
  const float* features = (const float*)d_in[0];
  const int*   y_true   = (const int*)d_in[1];
  const float* weight   = (const float*)d_in[2];
  float* out = (float*)d_out;

  char* ws = (char*)d_ws;
  char* wb8    = ws;                          // 16 MB
  char* fb8    = ws + 16777216;               //  1 MB
  float* tgt    = (float*)(ws + 17825792);    //  8 KB
  float* rowsum = (float*)(ws + 17833984);    //  8 KB

  prep_kernel<<<8192 + 512, 256, 0, stream>>>(features, y_true, weight,
                                              (int*)fb8, (int*)wb8, tgt, rowsum);
  gemm_exp_kernel<<<2048, 512, 0, stream>>>(fb8, wb8, rowsum);
  loss_kernel<<<1, 512, 0, stream>>>(tgt, rowsum, out);
}

// Round 9
// 154.897 us; speedup vs baseline: 2.0570x; 1.0241x over previous
//
#include <hip/hip_runtime.h>
#include <hip/hip_bf16.h>
#include <math.h>

// ArcFace loss, MI355X. B=2048, D=512, C=32768.
// R9: R8 fp8 GEMM + single-barrier ping-pong double buffer: loads for slab
// k+1 are issued at the top of iter k, so the barrier at iter k+1 drains
// loads that had a full compute phase (~155cyc MFMA + reads) in flight,
// instead of draining just-issued loads (R8: ~300cyc L2 latency exposed
// per slab x 8 slabs). Fragment LDS addresses hoisted out of the K-loop;
// the two K-32 MFMA halves interleaved with their reads. Layouts identical
// to R8 (absmax 0.0, conflicts 0, FETCH 12MB via XCD swizzle).

#define BN 2048
#define DK 512
#define CN 32768

typedef __attribute__((ext_vector_type(4))) float floatx4;
typedef __attribute__((ext_vector_type(2))) long longx2;

__device__ inline float dot4(floatx4 a, floatx4 b) {
  return a.x * b.x + a.y * b.y + a.z * b.z + a.w * b.w;
}

__device__ inline int pack_fp8x4(floatx4 v) {
  int r = __builtin_amdgcn_cvt_pk_fp8_f32(v.x, v.y, 0, false);
  r = __builtin_amdgcn_cvt_pk_fp8_f32(v.z, v.w, r, true);
  return r;
}

// dword j (0..15) of a 64B slab -> MFMA-ready position:
// q=(j>>1)&3 (8B piece), p=j>>3 (k-step), dest = q*4 + p*2 + (j&1)
__device__ inline int permute16(int j) {
  return ((j >> 1) & 3) * 4 + (j >> 3) * 2 + (j & 1);
}

__device__ inline void async_ld16(const void* g, void* l) {
  __builtin_amdgcn_global_load_lds(
      (const __attribute__((address_space(1))) void*)g,
      (__attribute__((address_space(3))) void*)l, 16, 0, 0);
}

// ---- kernel 1: fused prep -> fp8 rows (512 B each), MFMA-ready byte order.
__global__ void prep_kernel(const float* __restrict__ feat,
                            const int* __restrict__ y,
                            const float* __restrict__ w,
                            int* __restrict__ fb8,     // [BN][128] dwords
                            int* __restrict__ wb8,     // [CN][128] dwords
                            float* __restrict__ tgt,
                            float* __restrict__ rowsum) {
  const int wave = threadIdx.x >> 6;
  const int l = threadIdx.x & 63;
  const int d0 = ((l >> 4) * 16)       + permute16(l & 15);
  const int d1 = ((4 + (l >> 4)) * 16) + permute16(l & 15);
  if (blockIdx.x < 8192) {
    const int row = blockIdx.x * 4 + wave;
    const floatx4* src = (const floatx4*)(w + (size_t)row * DK);
    floatx4 v0 = src[l];
    floatx4 v1 = src[64 + l];
    float s = dot4(v0, v0) + dot4(v1, v1);
#pragma unroll
    for (int off = 1; off < 64; off <<= 1) s += __shfl_xor(s, off, 64);
    const float scale = 1.0f / fmaxf(sqrtf(s), 1e-12f);
    v0 *= scale; v1 *= scale;
    int* db = wb8 + (size_t)row * 128;
    db[d0] = pack_fp8x4(v0);
    db[d1] = pack_fp8x4(v1);
  } else {
    const int i = (blockIdx.x - 8192) * 4 + wave;
    const floatx4* src = (const floatx4*)(feat + (size_t)i * DK);
    floatx4 v0 = src[l];
    floatx4 v1 = src[64 + l];
    const int cls = y[i];
    const floatx4* wr = (const floatx4*)(w + (size_t)cls * DK);
    floatx4 w0 = wr[l], w1 = wr[64 + l];
    float s  = dot4(v0, v0) + dot4(v1, v1);
    float d  = dot4(v0, w0) + dot4(v1, w1);
    float wn = dot4(w0, w0) + dot4(w1, w1);
#pragma unroll
    for (int off = 1; off < 64; off <<= 1) {
      s  += __shfl_xor(s, off, 64);
      d  += __shfl_xor(d, off, 64);
      wn += __shfl_xor(wn, off, 64);
    }
    const float fscale = 1.0f / fmaxf(sqrtf(s), 1e-12f);
    v0 *= fscale; v1 *= fscale;
    int* db = fb8 + (size_t)i * 128;
    db[d0] = pack_fp8x4(v0);
    db[d1] = pack_fp8x4(v1);
    if (l == 0) {
      tgt[i] = d * fscale / fmaxf(sqrtf(wn), 1e-12f);
      rowsum[i] = 0.0f;
    }
  }
}

// ---- kernel 2: 128(M)x256(N) fp8 MFMA GEMM (16x16x32), ping-pong LDS,
// one barrier per K-64 slab, fused exp row-sum.
__launch_bounds__(512, 4)
__global__ void gemm_exp_kernel(const char* __restrict__ fb8,   // [BN][512] B
                                const char* __restrict__ wb8,   // [CN][512] B
                                float* __restrict__ rowsum) {
  __shared__ char As[2][128 * 64];   // 2 x  8 KB
  __shared__ char Bs[2][256 * 64];   // 2 x 16 KB
  __shared__ float lsum[128];

  const int tid  = threadIdx.x;
  const int wave = tid >> 6;
  const int lane = tid & 63;

  // XCD swizzle: n -> (x: M-tile 0..15, y: N-tile 0..127); XCD(n%8) owns y%8.
  const int n = blockIdx.x;
  const int tileM = ((n >> 3) & 15) * 128;
  const int tileN = (((n >> 7) << 3) | (n & 7)) * 256;

  const int wm = (wave >> 2) * 64;  // wave M offset (0 or 64)
  const int wn = (wave & 3) * 64;   // wave N offset (0..192)

  if (tid < 128) lsum[tid] = 0.0f;  // covered by first K-loop barrier

  floatx4 acc[4][4];
#pragma unroll
  for (int mi = 0; mi < 4; ++mi)
#pragma unroll
    for (int ni = 0; ni < 4; ++ni)
      acc[mi][ni] = (floatx4){0.f, 0.f, 0.f, 0.f};

  // staging (unchanged from R8): unit c -> row c>>2, stored pos c&3;
  // fetch global unit (c&3)^((row>>1)&3).
  const int mA = tid >> 2;
  const int uA = (tid & 3) ^ ((mA >> 1) & 3);
  const int mB1 = (512 + tid) >> 2;
  const int uB1 = (tid & 3) ^ ((mB1 >> 1) & 3);
  const char* gA  = fb8 + (size_t)(tileM + mA)  * DK + uA  * 16;
  const char* gB0 = wb8 + (size_t)(tileN + mA)  * DK + uA  * 16;   // rows 0..127
  const char* gB1 = wb8 + (size_t)(tileN + mB1) * DK + uB1 * 16;   // rows 128..255
  const int ldsA  = wave * 1024;         // wave-uniform LDS offsets
  const int ldsB0 = wave * 1024;
  const int ldsB1 = 8192 + wave * 1024;

  // hoisted fragment LDS byte-offsets (loop-invariant)
  const int mrow = lane & 15;
  const int q    = lane >> 4;
  int offA[4], offB[4];
#pragma unroll
  for (int mi = 0; mi < 4; ++mi) {
    const int row = wm + mi * 16 + mrow;
    offA[mi] = row * 64 + (q ^ ((row >> 1) & 3)) * 16;
  }
#pragma unroll
  for (int ni = 0; ni < 4; ++ni) {
    const int row = wn + ni * 16 + mrow;
    offB[ni] = row * 64 + (q ^ ((row >> 1) & 3)) * 16;
  }

  // prologue: stage slab 0 into buffer 0
  async_ld16(gA,  &As[0][ldsA]);
  async_ld16(gB0, &Bs[0][ldsB0]);
  async_ld16(gB1, &Bs[0][ldsB1]);
  gA += 64; gB0 += 64; gB1 += 64;

#pragma unroll
  for (int kk = 0; kk < DK / 64; ++kk) {
    const int cur = kk & 1;
    // Barrier: (a) drains this wave's vmcnt -> buf[cur] resident (its loads
    // were issued one full iteration ago); (b) all waves done with buf[cur^1].
    __syncthreads();
    if (kk < DK / 64 - 1) {
      const int nxt = cur ^ 1;
      async_ld16(gA,  &As[nxt][ldsA]);
      async_ld16(gB0, &Bs[nxt][ldsB0]);
      async_ld16(gB1, &Bs[nxt][ldsB1]);
      gA += 64; gB0 += 64; gB1 += 64;
    }

    const char* Ab = As[cur];
    const char* Bb = Bs[cur];
    long af0[4], af1[4], bf0[4], bf1[4];
#pragma unroll
    for (int mi = 0; mi < 4; ++mi) {
      longx2 t = *(const longx2*)(Ab + offA[mi]);
      af0[mi] = t.x; af1[mi] = t.y;
    }
#pragma unroll
    for (int ni = 0; ni < 4; ++ni) {
      longx2 t = *(const longx2*)(Bb + offB[ni]);
      bf0[ni] = t.x; bf1[ni] = t.y;
    }
    // first K-32 half can start as soon as its reads land (fine lgkmcnt)
#pragma unroll
    for (int mi = 0; mi < 4; ++mi)
#pragma unroll
      for (int ni = 0; ni < 4; ++ni)
        acc[mi][ni] = __builtin_amdgcn_mfma_f32_16x16x32_fp8_fp8(
            af0[mi], bf0[ni], acc[mi][ni], 0, 0, 0);
#pragma unroll
    for (int mi = 0; mi < 4; ++mi)
#pragma unroll
      for (int ni = 0; ni < 4; ++ni)
        acc[mi][ni] = __builtin_amdgcn_mfma_f32_16x16x32_fp8_fp8(
            af1[mi], bf1[ni], acc[mi][ni], 0, 0, 0);
  }

  // epilogue: rowsum[m] += sum_n exp(64 * wf[m][n])
  const int rowq = (lane >> 4) * 4;  // C/D layout: row = quad*4 + reg
#pragma unroll
  for (int mi = 0; mi < 4; ++mi) {
#pragma unroll
    for (int r = 0; r < 4; ++r) {
      float v = 0.f;
#pragma unroll
      for (int ni = 0; ni < 4; ++ni)
        v += __expf(64.0f * acc[mi][ni][r]);
      v += __shfl_xor(v, 1, 64);
      v += __shfl_xor(v, 2, 64);
      v += __shfl_xor(v, 4, 64);
      v += __shfl_xor(v, 8, 64);
      if ((lane & 15) == 0)
        atomicAdd(&lsum[wm + mi * 16 + rowq + r], v);
    }
  }
  __syncthreads();
  if (tid < 128)
    atomicAdd(&rowsum[tileM + tid], lsum[tid]);
}

// ---- kernel 3: final loss
__global__ void loss_kernel(const float* __restrict__ tgt,
                            const float* __restrict__ rowsum,
                            float* __restrict__ out) {
  __shared__ float wsum[8];
  const int t = threadIdx.x;
  float sum = 0.f;
  const float cM = 0.87758256189037271f;  // cos(0.5)
  const float sM = 0.47942553860420301f;  // sin(0.5)
  for (int i = t; i < BN; i += 512) {
    const float tg_raw = tgt[i];
    const float tg = fminf(fmaxf(tg_raw, -1.f + 1e-7f), 1.f - 1e-7f);
    const float num = 64.f * (tg * cM - sqrtf(fmaxf(1.f - tg * tg, 0.f)) * sM);
    const float den = expf(num) + rowsum[i] - expf(64.f * tg_raw);
    sum += num - logf(den);
  }
#pragma unroll
  for (int off = 1; off < 64; off <<= 1) sum += __shfl_xor(sum, off, 64);
  if ((t & 63) == 0) wsum[t >> 6] = sum;
  __syncthreads();
  if (t == 0) {
    float tot = 0.f;
#pragma unroll
    for (int k = 0; k < 8; ++k) tot += wsum[k];
    out[0] = -tot * (1.0f / (float)BN);
  }
}

extern "C" void kernel_launch(void* const* d_in, const int* in_sizes, int n_in,
                              void* d_out, int out_size, void* d_ws, size_t ws_size,
                              hipStream_t stream) {
  const float* features = (const float*)d_in[0];
  const int*   y_true   = (const int*)d_in[1];
  const float* weight   = (const float*)d_in[2];
  float* out = (float*)d_out;

  char* ws = (char*)d_ws;
  char* wb8    = ws;                          // 16 MB
  char* fb8    = ws + 16777216;               //  1 MB
  float* tgt    = (float*)(ws + 17825792);    //  8 KB
  float* rowsum = (float*)(ws + 17833984);    //  8 KB

  prep_kernel<<<8192 + 512, 256, 0, stream>>>(features, y_true, weight,
                                              (int*)fb8, (int*)wb8, tgt, rowsum);
  gemm_exp_kernel<<<2048, 512, 0, stream>>>(fb8, wb8, rowsum);
  loss_kernel<<<1, 512, 0, stream>>>(tgt, rowsum, out);
}